// Round 4
// baseline (362.040 us; speedup 1.0000x reference)
//
#include <hip/hip_runtime.h>
#include <hip/hip_bf16.h>

// Problem constants (P=1 folded out everywhere)
#define NB   8      // batch
#define NA   8      // actions
#define ND   8      // dim_qk
#define NCH  64     // NA*ND q/k channels
#define GT   32     // grid T=H=W
#define KREG 216    // 6^3 halo voxels
#define KSTR 68     // (fallback kernel) kS row stride in floats
#define VSTR 9      // (fallback kernel) vS row stride
#define WROW 28     // weight row: 27 taps + 1 zero pad

// ws layout (floats): wq [128][WROW] @0, wv [8][WROW] @WV_OFF, dtype flag @FLAG_OFF
#define WV_OFF   (128 * WROW)          // 3584
#define FLAG_OFF (WV_OFF + 8 * WROW)   // 3808
// kv cache: starts at byte 16384 in ws. Row per voxel = 9 units of 16B:
//   units 0..7 = k ch 0..63 (fp16), unit 8 = v ch 0..7 (fp16). 144 B/voxel.
#define KV_OFF_BYTES 16384
#define KV_ROW_BYTES 144
#define KV_BYTES ((size_t)NB * 32768 * KV_ROW_BYTES)  // 37,748,736

typedef _Float16 h2_t __attribute__((ext_vector_type(2)));

static __device__ __forceinline__ unsigned pack_h2(float a, float b) {
    unsigned short ha = __builtin_bit_cast(unsigned short, (_Float16)a);
    unsigned short hb = __builtin_bit_cast(unsigned short, (_Float16)b);
    return (unsigned)ha | ((unsigned)hb << 16);
}

static __device__ __forceinline__ float dot2(unsigned k, unsigned q, float c) {
#if __has_builtin(__builtin_amdgcn_fdot2)
    return __builtin_amdgcn_fdot2(__builtin_bit_cast(h2_t, k),
                                  __builtin_bit_cast(h2_t, q), c, false);
#else
    h2_t a = __builtin_bit_cast(h2_t, k), b = __builtin_bit_cast(h2_t, q);
    return c + (float)a[0] * (float)b[0] + (float)a[1] * (float)b[1];
#endif
}

__global__ void prep_weights(const void* __restrict__ values,
                             const void* __restrict__ w_qk,
                             const void* __restrict__ w_v,
                             float* __restrict__ ws) {
    __shared__ int saneCnt;
    int t = threadIdx.x;  // 0..127
    if (t == 0) saneCnt = 0;
    __syncthreads();
    // input dtype armor (expect fp32; bf16 would be ~all-sane exponents)
    {
        const unsigned short* u16 = (const unsigned short*)values;
        int cnt = 0;
        for (int j = 0; j < 2; ++j) {
            unsigned short u = u16[((t * 2 + j) * 911) & (262144 - 1)];
            int e = (u >> 7) & 0xFF;
            if (e == 0 || (e >= 100 && e <= 150)) cnt++;
        }
        atomicAdd(&saneCnt, cnt);
    }
    __syncthreads();
    const bool isbf = (saneCnt >= 230);
    if (t == 0) ws[FLAG_OFF] = isbf ? 1.f : 0.f;

    if (isbf) {
        const __hip_bfloat16* w = (const __hip_bfloat16*)w_qk;
        for (int j = 0; j < 27; ++j)
            ws[t * WROW + j] = __bfloat162float(w[t * 27 + j]);
    } else {
        const float* w = (const float*)w_qk;
        for (int j = 0; j < 27; ++j)
            ws[t * WROW + j] = w[t * 27 + j];
    }
    ws[t * WROW + 27] = 0.f;

    if (t < NA) {
        float r[27], m = -1e30f;
        if (isbf) {
            const __hip_bfloat16* w = (const __hip_bfloat16*)w_v;
            for (int j = 0; j < 27; ++j) r[j] = __bfloat162float(w[t * 27 + j]);
        } else {
            const float* w = (const float*)w_v;
            for (int j = 0; j < 27; ++j) r[j] = w[t * 27 + j];
        }
        for (int j = 0; j < 27; ++j) m = fmaxf(m, r[j]);
        float s = 0.f;
        for (int j = 0; j < 27; ++j) { r[j] = __expf(r[j] - m); s += r[j]; }
        float inv = 1.f / s;
        for (int j = 0; j < 27; ++j) ws[WV_OFF + t * WROW + j] = r[j] * inv;
        ws[WV_OFF + t * WROW + 27] = 0.f;
    }
}

// ---------------- Pass 1: k/v conv for every voxel, fp16-packed ----------------
// grid: NB*512 blocks (4^3 tiles), 256 threads = 64 voxels x 4 ch-groups.
// thread (vox, g): k channels [16g,16g+16) + v channels [2g,2g+2).
__launch_bounds__(256, 4)
__global__ void kv_pass1(const void* __restrict__ values,
                         const void* __restrict__ rewards,
                         const float* __restrict__ ws,
                         char* __restrict__ kv) {
    __shared__ float xS[KREG];  // 6^3 x halo, origin g0-1
    const int tid  = threadIdx.x;
    const int bb   = blockIdx.x >> 9;
    const int tile = blockIdx.x & 511;
    const int tz = tile >> 6, ty = (tile >> 3) & 7, tx = tile & 7;
    const int g0z = tz * 4, g0y = ty * 4, g0x = tx * 4;
    const int base_in = bb * (GT * GT * GT);
    const bool isbf = (ws[FLAG_OFF] != 0.f);

    if (tid < KREG) {
        int hz = tid / 36, r2 = tid - hz * 36, hy = r2 / 6, hx = r2 - hy * 6;
        int gz = g0z + hz - 1, gy = g0y + hy - 1, gx = g0x + hx - 1;
        float v = 0.f;
        if ((unsigned)gz < 32u && (unsigned)gy < 32u && (unsigned)gx < 32u) {
            int idx = base_in + gz * 1024 + gy * 32 + gx;
            if (isbf) {
                v = __bfloat162float(((const __hip_bfloat16*)values)[idx]) +
                    __bfloat162float(((const __hip_bfloat16*)rewards)[idx]);
            } else {
                v = ((const float*)values)[idx] + ((const float*)rewards)[idx];
            }
        }
        xS[tid] = v;
    }
    __syncthreads();

    const int vox = tid >> 2, g = tid & 3;
    const int vz = vox >> 4, vy = (vox >> 2) & 3, vx = vox & 3;

    float xr[27];
    #pragma unroll
    for (int t = 0; t < 27; ++t) {
        int dz = t / 9, dy = (t / 3) % 3, dx = t % 3;
        xr[t] = xS[(vz + dz) * 36 + (vy + dy) * 6 + (vx + dx)];
    }

    size_t gvidx = (size_t)bb * 32768 +
                   (size_t)((g0z + vz) * 1024 + (g0y + vy) * 32 + (g0x + vx));
    char* row = kv + gvidx * KV_ROW_BYTES;

    // k channels [16g, 16g+16): w_qk rows 64..127
    const float* wk = ws + (NCH + g * 16) * WROW;
    #pragma unroll
    for (int half = 0; half < 2; ++half) {
        float c8[8];
        #pragma unroll
        for (int j = 0; j < 8; ++j) {
            const float* w = wk + (half * 8 + j) * WROW;
            float acc = 0.f;
            #pragma unroll
            for (int t = 0; t < 27; ++t) acc = fmaf(w[t], xr[t], acc);
            c8[j] = acc;
        }
        int4 u;
        u.x = pack_h2(c8[0], c8[1]);
        u.y = pack_h2(c8[2], c8[3]);
        u.z = pack_h2(c8[4], c8[5]);
        u.w = pack_h2(c8[6], c8[7]);
        *(int4*)(row + g * 32 + half * 16) = u;
    }
    // v channels 2g, 2g+1 (softmaxed weights)
    {
        float v2[2];
        #pragma unroll
        for (int j = 0; j < 2; ++j) {
            const float* w = ws + WV_OFF + (2 * g + j) * WROW;
            float acc = 0.f;
            #pragma unroll
            for (int t = 0; t < 27; ++t) acc = fmaf(w[t], xr[t], acc);
            v2[j] = acc;
        }
        *(unsigned*)(row + 128 + g * 4) = pack_h2(v2[0], v2[1]);
    }
}

// ---------------- Pass 2: q + neighborhood attention ----------------
__launch_bounds__(256, 4)
__global__ void avi_pass2(const void* __restrict__ values,
                          const void* __restrict__ rewards,
                          const float* __restrict__ ws,
                          const char* __restrict__ kv,
                          float* __restrict__ out) {
    __shared__ float xS[KREG];               // 6^3 x halo (for q conv)
    __shared__ int4  kvS[KREG * 9];          // 6^3 kv halo rows (31.1 KB)
    __shared__ float outP[256];

    const int tid  = threadIdx.x;
    const int bb   = blockIdx.x >> 9;
    const int tile = blockIdx.x & 511;
    const int tz = tile >> 6, ty = (tile >> 3) & 7, tx = tile & 7;
    const int g0z = tz * 4, g0y = ty * 4, g0x = tx * 4;
    const int base_in = bb * (GT * GT * GT);
    const bool isbf = (ws[FLAG_OFF] != 0.f);

    if (tid < KREG) {
        int hz = tid / 36, r2 = tid - hz * 36, hy = r2 / 6, hx = r2 - hy * 6;
        int gz = g0z + hz - 1, gy = g0y + hy - 1, gx = g0x + hx - 1;
        float v = 0.f;
        if ((unsigned)gz < 32u && (unsigned)gy < 32u && (unsigned)gx < 32u) {
            int idx = base_in + gz * 1024 + gy * 32 + gx;
            if (isbf) {
                v = __bfloat162float(((const __hip_bfloat16*)values)[idx]) +
                    __bfloat162float(((const __hip_bfloat16*)rewards)[idx]);
            } else {
                v = ((const float*)values)[idx] + ((const float*)rewards)[idx];
            }
        }
        xS[tid] = v;
    }
    // stage kv halo: 216 rows x 9 units; OOB rows -> 0
    for (int i = tid; i < KREG * 9; i += 256) {
        int rrow = i / 9, u = i - rrow * 9;
        int hz = rrow / 36, r2 = rrow - hz * 36, hy = r2 / 6, hx = r2 - hy * 6;
        int gz = g0z + hz - 1, gy = g0y + hy - 1, gx = g0x + hx - 1;
        int4 val = make_int4(0, 0, 0, 0);
        if ((unsigned)gz < 32u && (unsigned)gy < 32u && (unsigned)gx < 32u) {
            size_t gv = (size_t)bb * 32768 +
                        (size_t)(gz * 1024 + gy * 32 + gx);
            val = *(const int4*)(kv + gv * KV_ROW_BYTES + u * 16);
        }
        kvS[i] = val;
    }
    __syncthreads();

    const int lane = tid & 63;
    const int wave = tid >> 6;
    const int lz = lane >> 4, ly = (lane >> 2) & 3, lx = lane & 3;

    float xr[27];
    #pragma unroll
    for (int t = 0; t < 27; ++t) {
        int dz = t / 9, dy = (t / 3) % 3, dx = t % 3;
        xr[t] = xS[(lz + dz) * 36 + (ly + dy) * 6 + (lx + dx)];
    }

    float res[2];
    #pragma unroll
    for (int ti = 0; ti < 2; ++ti) {
        int a = wave + ti * 4;                 // wave-uniform
        const float* wq = ws + a * ND * WROW;  // q rows 0..63
        float q[ND];
        #pragma unroll
        for (int d = 0; d < ND; ++d) {
            float acc = 0.f;
            #pragma unroll
            for (int t = 0; t < 27; ++t) acc = fmaf(wq[d * WROW + t], xr[t], acc);
            q[d] = acc;
        }
        unsigned qp[4];
        #pragma unroll
        for (int j = 0; j < 4; ++j) qp[j] = pack_h2(q[2 * j], q[2 * j + 1]);

        float sim[27];
        float m = -1e30f;
        #pragma unroll
        for (int n = 0; n < 27; ++n) {
            int dz = n / 9, dy = (n / 3) % 3, dx = n % 3;
            int r = (lz + dz) * 36 + (ly + dy) * 6 + (lx + dx);
            int4 kr = kvS[r * 9 + a];
            float s = dot2((unsigned)kr.x, qp[0],
                      dot2((unsigned)kr.y, qp[1],
                      dot2((unsigned)kr.z, qp[2],
                      dot2((unsigned)kr.w, qp[3], 0.f))));
            sim[n] = s;
            m = fmaxf(m, s);
        }
        float ssum = 0.f, acc = 0.f;
        #pragma unroll
        for (int n = 0; n < 27; ++n) {
            int dz = n / 9, dy = (n / 3) % 3, dx = n % 3;
            int r = (lz + dz) * 36 + (ly + dy) * 6 + (lx + dx);
            float e = __expf(sim[n] - m);
            ssum += e;
            const unsigned short* vr = (const unsigned short*)&kvS[r * 9 + 8];
            float fv = (float)__builtin_bit_cast(_Float16, vr[a]);
            acc = fmaf(e, fv, acc);
        }
        res[ti] = acc / ssum;
    }
    outP[lane * 4 + wave] = fmaxf(res[0], res[1]);
    __syncthreads();

    if (tid < 64) {
        float4 p = *(const float4*)(outP + tid * 4);
        float mx = fmaxf(fmaxf(p.x, p.y), fmaxf(p.z, p.w));
        int lz2 = tid >> 4, ly2 = (tid >> 2) & 3, lx2 = tid & 3;
        int o = base_in + (g0z + lz2) * 1024 + (g0y + ly2) * 32 + (g0x + lx2);
        out[o] = mx;
    }
}

// ---------------- Fallback: verified fused kernel (round 3) ----------------
__launch_bounds__(256, 2)
__global__ void avi_kernel(const void* __restrict__ values,
                           const void* __restrict__ rewards,
                           const float* __restrict__ ws,
                           float* __restrict__ out) {
    __shared__ __align__(16) float xS[512];
    __shared__ __align__(16) float kS[KREG * KSTR];
    __shared__ __align__(16) float vS[KREG * VSTR];
    __shared__ __align__(16) float outP[64 * 4];

    const int tid  = threadIdx.x;
    const int bb   = blockIdx.x >> 9;
    const int tile = blockIdx.x & 511;
    const int tz = tile >> 6, ty = (tile >> 3) & 7, tx = tile & 7;
    const int g0z = tz * 4, g0y = ty * 4, g0x = tx * 4;
    const int base_in = bb * (GT * GT * GT);
    const bool isbf = (ws[FLAG_OFF] != 0.f);

    for (int i = tid; i < 512; i += 256) {
        int lz = i >> 6, ly = (i >> 3) & 7, lx = i & 7;
        int gz = g0z + lz - 2, gy = g0y + ly - 2, gx = g0x + lx - 2;
        float v = 0.f;
        if ((unsigned)gz < 32u && (unsigned)gy < 32u && (unsigned)gx < 32u) {
            int idx = base_in + gz * 1024 + gy * 32 + gx;
            if (isbf) {
                v = __bfloat162float(((const __hip_bfloat16*)values)[idx]) +
                    __bfloat162float(((const __hip_bfloat16*)rewards)[idx]);
            } else {
                v = ((const float*)values)[idx] + ((const float*)rewards)[idx];
            }
        }
        xS[i] = v;
    }
    __syncthreads();

    if (tid < KREG) {
        int vz = tid / 36, rem = tid - vz * 36, vy = rem / 6, vx = rem - vy * 6;
        int gz = g0z + vz - 1, gy = g0y + vy - 1, gx = g0x + vx - 1;
        float mask = ((unsigned)gz < 32u && (unsigned)gy < 32u && (unsigned)gx < 32u)
                         ? 1.f : 0.f;
        float xr[WROW];
        #pragma unroll
        for (int t = 0; t < 27; ++t) {
            int dz = t / 9, dy = (t / 3) % 3, dx = t % 3;
            xr[t] = xS[(vz + dz) * 64 + (vy + dy) * 8 + (vx + dx)];
        }
        xr[27] = 0.f;
        const float* wk = ws + NCH * WROW;
        int kbase = tid * KSTR;
        for (int c4 = 0; c4 < 16; ++c4) {
            float4 o;
            #pragma unroll
            for (int j = 0; j < 4; ++j) {
                const float* w = wk + (c4 * 4 + j) * WROW;
                float acc = 0.f;
                #pragma unroll
                for (int t = 0; t < WROW; ++t) acc = fmaf(w[t], xr[t], acc);
                ((float*)&o)[j] = acc * mask;
            }
            *(float4*)(kS + kbase + c4 * 4) = o;
        }
        #pragma unroll
        for (int c = 0; c < NA; ++c) {
            const float* w = ws + WV_OFF + c * WROW;
            float acc = 0.f;
            #pragma unroll
            for (int t = 0; t < WROW; ++t) acc = fmaf(w[t], xr[t], acc);
            vS[tid * VSTR + c] = acc * mask;
        }
    }
    __syncthreads();

    const int lane = tid & 63;
    const int wave = tid >> 6;
    const int lz = lane >> 4, ly = (lane >> 2) & 3, lx = lane & 3;

    float xr[WROW];
    #pragma unroll
    for (int t = 0; t < 27; ++t) {
        int dz = t / 9, dy = (t / 3) % 3, dx = t % 3;
        xr[t] = xS[(lz + 1 + dz) * 64 + (ly + 1 + dy) * 8 + (lx + 1 + dx)];
    }
    xr[27] = 0.f;

    float res[2];
    #pragma unroll
    for (int ti = 0; ti < 2; ++ti) {
        int a = wave + ti * 4;
        const float* wq = ws + a * ND * WROW;
        float q[ND];
        #pragma unroll
        for (int d = 0; d < ND; ++d) {
            float acc = 0.f;
            #pragma unroll
            for (int t = 0; t < WROW; ++t) acc = fmaf(wq[d * WROW + t], xr[t], acc);
            q[d] = acc;
        }
        float sim[27];
        float m = -1e30f;
        #pragma unroll
        for (int n = 0; n < 27; ++n) {
            int dz = n / 9, dy = (n / 3) % 3, dx = n % 3;
            int kn = (lz + dz) * 36 + (ly + dy) * 6 + (lx + dx);
            const float4* kp = (const float4*)(kS + kn * KSTR + a * ND);
            float4 k0 = kp[0], k1 = kp[1];
            float s = q[0] * k0.x;
            s = fmaf(q[1], k0.y, s);
            s = fmaf(q[2], k0.z, s);
            s = fmaf(q[3], k0.w, s);
            s = fmaf(q[4], k1.x, s);
            s = fmaf(q[5], k1.y, s);
            s = fmaf(q[6], k1.z, s);
            s = fmaf(q[7], k1.w, s);
            sim[n] = s;
            m = fmaxf(m, s);
        }
        float ssum = 0.f, acc = 0.f;
        #pragma unroll
        for (int n = 0; n < 27; ++n) {
            int dz = n / 9, dy = (n / 3) % 3, dx = n % 3;
            int kn = (lz + dz) * 36 + (ly + dy) * 6 + (lx + dx);
            float e = __expf(sim[n] - m);
            ssum += e;
            acc = fmaf(e, vS[kn * VSTR + a], acc);
        }
        res[ti] = acc / ssum;
    }
    outP[lane * 4 + wave] = fmaxf(res[0], res[1]);
    __syncthreads();

    if (tid < 64) {
        float4 p = *(const float4*)(outP + tid * 4);
        float mx = fmaxf(fmaxf(p.x, p.y), fmaxf(p.z, p.w));
        int lz2 = tid >> 4, ly2 = (tid >> 2) & 3, lx2 = tid & 3;
        int o = base_in + (g0z + lz2) * 1024 + (g0y + ly2) * 32 + (g0x + lx2);
        out[o] = mx;
    }
}

extern "C" void kernel_launch(void* const* d_in, const int* in_sizes, int n_in,
                              void* d_out, int out_size, void* d_ws, size_t ws_size,
                              hipStream_t stream) {
    const void* values  = d_in[0];
    const void* rewards = d_in[1];
    const void* w_qk    = d_in[2];
    const void* w_v     = d_in[3];
    float* ws = (float*)d_ws;

    prep_weights<<<1, 128, 0, stream>>>(values, w_qk, w_v, ws);

    const size_t needed = KV_OFF_BYTES + KV_BYTES;
    if (ws_size >= needed) {
        char* kv = (char*)d_ws + KV_OFF_BYTES;
        kv_pass1<<<NB * 512, 256, 0, stream>>>(values, rewards, ws, kv);
        avi_pass2<<<NB * 512, 256, 0, stream>>>(values, rewards, ws, kv,
                                                (float*)d_out);
    } else {
        avi_kernel<<<NB * 512, 256, 0, stream>>>(values, rewards, ws,
                                                 (float*)d_out);
    }
}

// Round 5
// 175.084 us; speedup vs baseline: 2.0678x; 2.0678x over previous
//
#include <hip/hip_runtime.h>
#include <hip/hip_bf16.h>

// Problem constants (P=1 folded out everywhere)
#define NB   8      // batch
#define NA   8      // actions
#define ND   8      // dim_qk
#define NCH  64     // NA*ND q/k channels
#define GT   32     // grid T=H=W
#define KREG 216    // 6^3 halo voxels
#define WROW 28     // weight row: 27 taps + 1 zero pad

// ws layout (floats): wq [128][WROW] @0, wv [8][WROW] @WV_OFF, dtype flag @FLAG_OFF
#define WV_OFF   (128 * WROW)          // 3584
#define FLAG_OFF (WV_OFF + 8 * WROW)   // 3808

typedef _Float16 h2_t __attribute__((ext_vector_type(2)));

static __device__ __forceinline__ unsigned pack_h2(float a, float b) {
    unsigned short ha = __builtin_bit_cast(unsigned short, (_Float16)a);
    unsigned short hb = __builtin_bit_cast(unsigned short, (_Float16)b);
    return (unsigned)ha | ((unsigned)hb << 16);
}

static __device__ __forceinline__ float dot2(unsigned k, unsigned q, float c) {
#if __has_builtin(__builtin_amdgcn_fdot2)
    return __builtin_amdgcn_fdot2(__builtin_bit_cast(h2_t, k),
                                  __builtin_bit_cast(h2_t, q), c, false);
#else
    h2_t a = __builtin_bit_cast(h2_t, k), b = __builtin_bit_cast(h2_t, q);
    return c + (float)a[0] * (float)b[0] + (float)a[1] * (float)b[1];
#endif
}

__global__ void prep_weights(const void* __restrict__ values,
                             const void* __restrict__ w_qk,
                             const void* __restrict__ w_v,
                             float* __restrict__ ws) {
    __shared__ int saneCnt;
    int t = threadIdx.x;  // 0..127
    if (t == 0) saneCnt = 0;
    __syncthreads();
    // input dtype armor (expect fp32; bf16 storage would be ~all-sane exponents)
    {
        const unsigned short* u16 = (const unsigned short*)values;
        int cnt = 0;
        for (int j = 0; j < 2; ++j) {
            unsigned short u = u16[((t * 2 + j) * 911) & (262144 - 1)];
            int e = (u >> 7) & 0xFF;
            if (e == 0 || (e >= 100 && e <= 150)) cnt++;
        }
        atomicAdd(&saneCnt, cnt);
    }
    __syncthreads();
    const bool isbf = (saneCnt >= 230);
    if (t == 0) ws[FLAG_OFF] = isbf ? 1.f : 0.f;

    if (isbf) {
        const __hip_bfloat16* w = (const __hip_bfloat16*)w_qk;
        for (int j = 0; j < 27; ++j)
            ws[t * WROW + j] = __bfloat162float(w[t * 27 + j]);
    } else {
        const float* w = (const float*)w_qk;
        for (int j = 0; j < 27; ++j)
            ws[t * WROW + j] = w[t * 27 + j];
    }
    ws[t * WROW + 27] = 0.f;

    if (t < NA) {
        float r[27], m = -1e30f;
        if (isbf) {
            const __hip_bfloat16* w = (const __hip_bfloat16*)w_v;
            for (int j = 0; j < 27; ++j) r[j] = __bfloat162float(w[t * 27 + j]);
        } else {
            const float* w = (const float*)w_v;
            for (int j = 0; j < 27; ++j) r[j] = w[t * 27 + j];
        }
        for (int j = 0; j < 27; ++j) m = fmaxf(m, r[j]);
        float s = 0.f;
        for (int j = 0; j < 27; ++j) { r[j] = __expf(r[j] - m); s += r[j]; }
        float inv = 1.f / s;
        for (int j = 0; j < 27; ++j) ws[WV_OFF + t * WROW + j] = r[j] * inv;
        ws[WV_OFF + t * WROW + 27] = 0.f;
    }
}

// Fused kernel, round-3 structure + fp16 LDS k/v rows (144 B) -> 4 blocks/CU.
// kvS row r (halo voxel): units 0..7 = k ch pairs (fp16x2 x4 per unit),
// unit 8 = v ch 0..7 fp16. Phase-C b128 unit index == (r + a) mod 8 with
// r == lx + 6*ly + 4*lz (mod 8): uniform 8 lanes/unit-group = b128 floor.
__launch_bounds__(256, 4)
__global__ void avi_kernel(const void* __restrict__ values,
                           const void* __restrict__ rewards,
                           const float* __restrict__ ws,
                           float* __restrict__ out) {
    __shared__ __align__(16) float xS[512];        // 8^3 x tile, origin g0-2
    __shared__ __align__(16) int4  kvS[KREG * 9];  // 31.1 KB fp16 k/v halo
    __shared__ __align__(16) float outP[256];

    const int tid  = threadIdx.x;
    const int bb   = blockIdx.x >> 9;      // batch
    const int tile = blockIdx.x & 511;     // 8x8x8 tiles of 4^3
    const int tz = tile >> 6, ty = (tile >> 3) & 7, tx = tile & 7;
    const int g0z = tz * 4, g0y = ty * 4, g0x = tx * 4;
    const int base_in = bb * (GT * GT * GT);
    const bool isbf = (ws[FLAG_OFF] != 0.f);  // uniform branch

    // ---- Phase A: stage x = values + rewards (fp32), zero outside grid ----
    for (int i = tid; i < 512; i += 256) {
        int lz = i >> 6, ly = (i >> 3) & 7, lx = i & 7;
        int gz = g0z + lz - 2, gy = g0y + ly - 2, gx = g0x + lx - 2;
        float v = 0.f;
        if ((unsigned)gz < 32u && (unsigned)gy < 32u && (unsigned)gx < 32u) {
            int idx = base_in + gz * 1024 + gy * 32 + gx;
            if (isbf) {
                v = __bfloat162float(((const __hip_bfloat16*)values)[idx]) +
                    __bfloat162float(((const __hip_bfloat16*)rewards)[idx]);
            } else {
                v = ((const float*)values)[idx] + ((const float*)rewards)[idx];
            }
        }
        xS[i] = v;
    }
    __syncthreads();

    // ---- Phase B: k/v conv over 6^3 halo; wave-uniform weight addrs (s_load) ----
    if (tid < KREG) {
        int vz = tid / 36, rem = tid - vz * 36, vy = rem / 6, vx = rem - vy * 6;
        int gz = g0z + vz - 1, gy = g0y + vy - 1, gx = g0x + vx - 1;
        // k/v outside the global grid are exactly 0 (padding of conv OUTPUT)
        float mask = ((unsigned)gz < 32u && (unsigned)gy < 32u && (unsigned)gx < 32u)
                         ? 1.f : 0.f;
        float xr[27];
        #pragma unroll
        for (int t = 0; t < 27; ++t) {
            int dz = t / 9, dy = (t / 3) % 3, dx = t % 3;
            xr[t] = xS[(vz + dz) * 64 + (vy + dy) * 8 + (vx + dx)];
        }
        // k channels: w_qk rows 64..127 (second half = k weights)
        const float* wk = ws + NCH * WROW;
        #pragma unroll
        for (int u = 0; u < 8; ++u) {   // unit u = k channels 8u..8u+7
            float c8[8];
            #pragma unroll
            for (int j = 0; j < 8; ++j) {
                const float* w = wk + (u * 8 + j) * WROW;
                float acc = 0.f;
                #pragma unroll
                for (int t = 0; t < 27; ++t) acc = fmaf(w[t], xr[t], acc);
                c8[j] = acc * mask;
            }
            int4 o;
            o.x = pack_h2(c8[0], c8[1]);
            o.y = pack_h2(c8[2], c8[3]);
            o.z = pack_h2(c8[4], c8[5]);
            o.w = pack_h2(c8[6], c8[7]);
            kvS[tid * 9 + u] = o;
        }
        // v channels 0..7 (softmaxed weights) -> unit 8
        {
            float c8[8];
            #pragma unroll
            for (int j = 0; j < 8; ++j) {
                const float* w = ws + WV_OFF + j * WROW;
                float acc = 0.f;
                #pragma unroll
                for (int t = 0; t < 27; ++t) acc = fmaf(w[t], xr[t], acc);
                c8[j] = acc * mask;
            }
            int4 o;
            o.x = pack_h2(c8[0], c8[1]);
            o.y = pack_h2(c8[2], c8[3]);
            o.z = pack_h2(c8[4], c8[5]);
            o.w = pack_h2(c8[6], c8[7]);
            kvS[tid * 9 + 8] = o;
        }
    }
    __syncthreads();

    // ---- Phase C: q + neighborhood attention; a = waveId(+4) (wave-uniform) ----
    const int lane = tid & 63;
    const int wave = tid >> 6;
    const int lz = lane >> 4, ly = (lane >> 2) & 3, lx = lane & 3;

    float xr[27];
    #pragma unroll
    for (int t = 0; t < 27; ++t) {
        int dz = t / 9, dy = (t / 3) % 3, dx = t % 3;
        xr[t] = xS[(lz + 1 + dz) * 64 + (ly + 1 + dy) * 8 + (lx + 1 + dx)];
    }

    float res[2];
    #pragma unroll
    for (int ti = 0; ti < 2; ++ti) {
        int a = wave + ti * 4;                 // wave-uniform
        const float* wq = ws + a * ND * WROW;  // q weights: rows 0..63
        float q[ND];
        #pragma unroll
        for (int d = 0; d < ND; ++d) {
            float acc = 0.f;
            #pragma unroll
            for (int t = 0; t < 27; ++t) acc = fmaf(wq[d * WROW + t], xr[t], acc);
            q[d] = acc;
        }
        unsigned qp[4];
        #pragma unroll
        for (int j = 0; j < 4; ++j) qp[j] = pack_h2(q[2 * j], q[2 * j + 1]);

        float sim[27];
        float m = -1e30f;
        #pragma unroll
        for (int n = 0; n < 27; ++n) {
            int dz = n / 9, dy = (n / 3) % 3, dx = n % 3;
            int r = (lz + dz) * 36 + (ly + dy) * 6 + (lx + dx);
            int4 kr = kvS[r * 9 + a];
            float s = dot2((unsigned)kr.x, qp[0],
                      dot2((unsigned)kr.y, qp[1],
                      dot2((unsigned)kr.z, qp[2],
                      dot2((unsigned)kr.w, qp[3], 0.f))));
            sim[n] = s;
            m = fmaxf(m, s);
        }
        float ssum = 0.f, acc = 0.f;
        #pragma unroll
        for (int n = 0; n < 27; ++n) {
            int dz = n / 9, dy = (n / 3) % 3, dx = n % 3;
            int r = (lz + dz) * 36 + (ly + dy) * 6 + (lx + dx);
            float e = __expf(sim[n] - m);
            ssum += e;
            const unsigned short* vr = (const unsigned short*)&kvS[r * 9 + 8];
            float fv = (float)__builtin_bit_cast(_Float16, vr[a]);
            acc = fmaf(e, fv, acc);
        }
        res[ti] = acc / ssum;
    }
    outP[lane * 4 + wave] = fmaxf(res[0], res[1]);
    __syncthreads();

    // ---- max over actions (4 wave-partials) -> fp32 output ----
    if (tid < 64) {
        float4 p = *(const float4*)(outP + tid * 4);
        float mx = fmaxf(fmaxf(p.x, p.y), fmaxf(p.z, p.w));
        int lz2 = tid >> 4, ly2 = (tid >> 2) & 3, lx2 = tid & 3;
        int o = base_in + (g0z + lz2) * 1024 + (g0y + ly2) * 32 + (g0x + lx2);
        out[o] = mx;
    }
}

extern "C" void kernel_launch(void* const* d_in, const int* in_sizes, int n_in,
                              void* d_out, int out_size, void* d_ws, size_t ws_size,
                              hipStream_t stream) {
    const void* values  = d_in[0];
    const void* rewards = d_in[1];
    const void* w_qk    = d_in[2];
    const void* w_v     = d_in[3];
    float* ws = (float*)d_ws;  // ~15.3 KB used

    prep_weights<<<1, 128, 0, stream>>>(values, w_qk, w_v, ws);
    avi_kernel<<<NB * 512, 256, 0, stream>>>(values, rewards, ws,
                                             (float*)d_out);
}

// Round 7
// 138.262 us; speedup vs baseline: 2.6185x; 1.2663x over previous
//
#include <hip/hip_runtime.h>
#include <hip/hip_bf16.h>

// Problem constants (P=1 folded out everywhere)
#define NB   8      // batch
#define NA   8      // actions
#define ND   8      // dim_qk
#define NCH  64     // NA*ND q/k channels
#define GT   32     // grid T=H=W
#define KREG 216    // 6^3 halo voxels
#define IMS  40     // im2col row stride in halfwords (80 B, 16B-aligned)

typedef _Float16 h2_t  __attribute__((ext_vector_type(2)));
typedef _Float16 f16x8 __attribute__((ext_vector_type(8)));
typedef float    f32x4 __attribute__((ext_vector_type(4)));

static __device__ __forceinline__ unsigned pack_h2(float a, float b) {
#if __has_builtin(__builtin_amdgcn_cvt_pkrtz)
    return __builtin_bit_cast(unsigned, __builtin_amdgcn_cvt_pkrtz(a, b));
#else
    unsigned short ha = __builtin_bit_cast(unsigned short, (_Float16)a);
    unsigned short hb = __builtin_bit_cast(unsigned short, (_Float16)b);
    return (unsigned)ha | ((unsigned)hb << 16);
#endif
}

static __device__ __forceinline__ float dot2(unsigned k, unsigned q, float c) {
#if __has_builtin(__builtin_amdgcn_fdot2)
    return __builtin_amdgcn_fdot2(__builtin_bit_cast(h2_t, k),
                                  __builtin_bit_cast(h2_t, q), c, false);
#else
    h2_t a = __builtin_bit_cast(h2_t, k), b = __builtin_bit_cast(h2_t, q);
    return c + (float)a[0] * (float)b[0] + (float)a[1] * (float)b[1];
#endif
}

// Single fused kernel. Per 4^3 tile:
//  A:  stage x = values+rewards (fp32) into xS (8^3, origin g0-2); build BTS
//      (weights^T fp16 [80 rows=ch][32 cols=tap]; rows 0..63 = k-weights
//      (w_qk rows 64..127), 64..71 = softmax(w_v), 72..79 + cols 27..31 = 0).
//  B1: im2col x-taps fp16 [224 rows=halo-vox][IMS cols=tap] into uS (OOB vox
//      columns zeroed -> conv output mask folded in).
//  B2: MFMA 16x16x32_f16: D[ch][vox] = BTS . im2col^T; scatter fp16 into kvS
//      rows (144 B/vox: units 0..7 = k ch pairs, unit 8 = v) aliasing im2col.
//  C:  q conv fp32 (s_load weights from w_qk), 27-neighbor sims via v_dot2,
//      softmax, v-weighted sum; max over actions -> fp32 out.
__launch_bounds__(256, 4)
__global__ void avi_kernel(const float* __restrict__ values,
                           const float* __restrict__ rewards,
                           const float* __restrict__ w_qk,
                           const float* __restrict__ w_v,
                           float* __restrict__ out) {
    __shared__ __align__(16) float    xS[512];        // 2 KB
    __shared__ __align__(16) _Float16 BTS[80 * 32];   // 5 KB
    __shared__ __align__(16) char     uS[KREG * 144 + 1024];  // 31.4 KB union

    _Float16* imc  = (_Float16*)uS;           // [224][IMS], dead after B2 loads
    int4*     kvS  = (int4*)uS;               // [216][9] int4 units
    float*    outP = (float*)(uS + KREG * 144);

    const int tid  = threadIdx.x;
    const int bb   = blockIdx.x >> 9;      // batch
    const int tile = blockIdx.x & 511;     // 8x8x8 tiles of 4^3
    const int tz = tile >> 6, ty = (tile >> 3) & 7, tx = tile & 7;
    const int g0z = tz * 4, g0y = ty * 4, g0x = tx * 4;
    const int base_in = bb * (GT * GT * GT);

    // ---- Phase A: x staging + BTS build (independent, one barrier) ----
    for (int i = tid; i < 512; i += 256) {
        int lz = i >> 6, ly = (i >> 3) & 7, lx = i & 7;
        int gz = g0z + lz - 2, gy = g0y + ly - 2, gx = g0x + lx - 2;
        float v = 0.f;
        if ((unsigned)gz < 32u && (unsigned)gy < 32u && (unsigned)gx < 32u) {
            int idx = base_in + gz * 1024 + gy * 32 + gx;
            v = values[idx] + rewards[idx];
        }
        xS[i] = v;
    }
    // BTS zero pads (disjoint from fills below -> no race)
    for (int i = tid; i < 616; i += 256) {
        int row, col;
        if (i < 400) { row = i / 5; col = 27 + (i % 5); }
        else         { int j = i - 400; row = 72 + j / 27; col = j % 27; }
        BTS[row * 32 + col] = (_Float16)0.f;
    }
    // BTS k-weight fill: rows 0..63 <- w_qk rows 64..127
    for (int i = tid; i < 1728; i += 256) {
        int n = i / 27, k = i - n * 27;
        BTS[n * 32 + k] = (_Float16)w_qk[(NCH + n) * 27 + k];
    }
    // BTS v rows 64..71 <- softmax(w_v)
    if (tid < NA) {
        float r[27], m = -1e30f;
        #pragma unroll
        for (int j = 0; j < 27; ++j) { r[j] = w_v[tid * 27 + j]; m = fmaxf(m, r[j]); }
        float s = 0.f;
        #pragma unroll
        for (int j = 0; j < 27; ++j) { r[j] = __expf(r[j] - m); s += r[j]; }
        float inv = 1.f / s;
        #pragma unroll
        for (int j = 0; j < 27; ++j)
            BTS[(64 + tid) * 32 + j] = (_Float16)(r[j] * inv);
    }
    __syncthreads();

    // ---- Phase B1: im2col fp16 (rows 216..223 zero); mask folded in ----
    if (tid < 224) {
        unsigned rowU[16];
        if (tid < KREG) {
            int vz = tid / 36, rem = tid - vz * 36, vy = rem / 6, vx = rem - vy * 6;
            int gz = g0z + vz - 1, gy = g0y + vy - 1, gx = g0x + vx - 1;
            float mask = ((unsigned)gz < 32u && (unsigned)gy < 32u && (unsigned)gx < 32u)
                             ? 1.f : 0.f;
            float xr[27];
            #pragma unroll
            for (int t = 0; t < 27; ++t) {
                int dz = t / 9, dy = (t / 3) % 3, dx = t % 3;
                xr[t] = xS[(vz + dz) * 64 + (vy + dy) * 8 + (vx + dx)] * mask;
            }
            #pragma unroll
            for (int p = 0; p < 13; ++p) rowU[p] = pack_h2(xr[2 * p], xr[2 * p + 1]);
            rowU[13] = pack_h2(xr[26], 0.f);
            rowU[14] = rowU[15] = 0u;
        } else {
            #pragma unroll
            for (int p = 0; p < 16; ++p) rowU[p] = 0u;
        }
        int4* dst = (int4*)((char*)imc + tid * (IMS * 2));
        dst[0] = make_int4(rowU[0], rowU[1], rowU[2], rowU[3]);
        dst[1] = make_int4(rowU[4], rowU[5], rowU[6], rowU[7]);
        dst[2] = make_int4(rowU[8], rowU[9], rowU[10], rowU[11]);
        dst[3] = make_int4(rowU[12], rowU[13], rowU[14], rowU[15]);
    }

    const int lane = tid & 63;
    const int wave = tid >> 6;
    const int quad = lane >> 4;
    const int l15  = lane & 15;

    // A'-frags (weights): A[m=l15][k=quad*8+j] from BTS (ready after barrier 1)
    f16x8 af[5];
    #pragma unroll
    for (int mt = 0; mt < 5; ++mt)
        af[mt] = *(const f16x8*)(BTS + (mt * 16 + l15) * 32 + quad * 8);

    __syncthreads();   // im2col ready

    // B'-frags: B[k=quad*8+j][n=l15] = imc[row=n][col=k]; wave's nt tiles
    f16x8 bf[4];
    #pragma unroll
    for (int i = 0; i < 4; ++i) {
        int nt = wave + i * 4;
        if (nt < 14)
            bf[i] = *(const f16x8*)(imc + (nt * 16 + l15) * IMS + quad * 8);
    }

    __syncthreads();   // all frag loads done -> im2col LDS reusable as kvS

    // ---- Phase B2: MFMA + scatter into kvS ----
    for (int i = 0; i < 4; ++i) {
        int nt = wave + i * 4;
        if (nt >= 14) break;
        int n = nt * 16 + l15;
        bool nvalid = (n < KREG);
        char* rowB = uS + n * 144;
        #pragma unroll
        for (int mt = 0; mt < 5; ++mt) {
            f32x4 d = __builtin_amdgcn_mfma_f32_16x16x32_f16(
                af[mt], bf[i], (f32x4){0.f, 0.f, 0.f, 0.f}, 0, 0, 0);
            // lane's rows: ch = mt*16 + quad*4 + reg
            if (mt < 4) {
                if (nvalid) {
                    int2 w2;
                    w2.x = (int)pack_h2(d[0], d[1]);
                    w2.y = (int)pack_h2(d[2], d[3]);
                    *(int2*)(rowB + (mt * 16 + quad * 4) * 2) = w2;
                }
            } else {
                if (nvalid && quad < 2) {   // v channels 64..71
                    int2 w2;
                    w2.x = (int)pack_h2(d[0], d[1]);
                    w2.y = (int)pack_h2(d[2], d[3]);
                    *(int2*)(rowB + 128 + quad * 8) = w2;
                }
            }
        }
    }
    __syncthreads();

    // ---- Phase C: q + neighborhood attention; a = wave(+4) wave-uniform ----
    const int clz = lane >> 4, cly = (lane >> 2) & 3, clx = lane & 3;

    float xr[27];
    #pragma unroll
    for (int t = 0; t < 27; ++t) {
        int dz = t / 9, dy = (t / 3) % 3, dx = t % 3;
        xr[t] = xS[(clz + 1 + dz) * 64 + (cly + 1 + dy) * 8 + (clx + 1 + dx)];
    }

    float res[2];
    #pragma unroll
    for (int ti = 0; ti < 2; ++ti) {
        int a = wave + ti * 4;                    // wave-uniform -> s_load
        const float* wq = w_qk + a * ND * 27;     // q weights: rows 0..63
        float q[ND];
        #pragma unroll
        for (int d = 0; d < ND; ++d) {
            float acc = 0.f;
            #pragma unroll
            for (int t = 0; t < 27; ++t) acc = fmaf(wq[d * 27 + t], xr[t], acc);
            q[d] = acc;
        }
        unsigned qp[4];
        #pragma unroll
        for (int j = 0; j < 4; ++j) qp[j] = pack_h2(q[2 * j], q[2 * j + 1]);

        float sim[27];
        float m = -1e30f;
        #pragma unroll
        for (int nn = 0; nn < 27; ++nn) {
            int dz = nn / 9, dy = (nn / 3) % 3, dx = nn % 3;
            int r = (clz + dz) * 36 + (cly + dy) * 6 + (clx + dx);
            int4 kr = kvS[r * 9 + a];
            float s = dot2((unsigned)kr.x, qp[0],
                      dot2((unsigned)kr.y, qp[1],
                      dot2((unsigned)kr.z, qp[2],
                      dot2((unsigned)kr.w, qp[3], 0.f))));
            sim[nn] = s;
            m = fmaxf(m, s);
        }
        float ssum = 0.f, acc = 0.f;
        #pragma unroll
        for (int nn = 0; nn < 27; ++nn) {
            int dz = nn / 9, dy = (nn / 3) % 3, dx = nn % 3;
            int r = (clz + dz) * 36 + (cly + dy) * 6 + (clx + dx);
            float e = __expf(sim[nn] - m);
            ssum += e;
            const unsigned short* vr = (const unsigned short*)&kvS[r * 9 + 8];
            float fv = (float)__builtin_bit_cast(_Float16, vr[a]);
            acc = fmaf(e, fv, acc);
        }
        res[ti] = acc / ssum;
    }
    outP[lane * 4 + wave] = fmaxf(res[0], res[1]);
    __syncthreads();

    // ---- max over actions (4 wave-partials) -> fp32 output ----
    if (tid < 64) {
        float4 p = *(const float4*)(outP + tid * 4);
        float mx = fmaxf(fmaxf(p.x, p.y), fmaxf(p.z, p.w));
        int lz2 = tid >> 4, ly2 = (tid >> 2) & 3, lx2 = tid & 3;
        int o = base_in + (g0z + lz2) * 1024 + (g0y + ly2) * 32 + (g0x + lx2);
        out[o] = mx;
    }
}

extern "C" void kernel_launch(void* const* d_in, const int* in_sizes, int n_in,
                              void* d_out, int out_size, void* d_ws, size_t ws_size,
                              hipStream_t stream) {
    const float* values  = (const float*)d_in[0];
    const float* rewards = (const float*)d_in[1];
    const float* w_qk    = (const float*)d_in[2];
    const float* w_v     = (const float*)d_in[3];
    avi_kernel<<<NB * 512, 256, 0, stream>>>(values, rewards, w_qk, w_v,
                                             (float*)d_out);
}